// Round 1
// baseline (602.105 us; speedup 1.0000x reference)
//
#include <hip/hip_runtime.h>

typedef float f32x4 __attribute__((ext_vector_type(4)));
typedef __bf16 bf16x8 __attribute__((ext_vector_type(8)));
typedef unsigned short u16;

#define DIM 2048
#define SEQ 1024
#define BSZ 2
#define NH 16
#define NKV 4
#define HD 128
#define FFNDIM 5632
#define MROWS (BSZ * SEQ)  // 2048

__device__ __forceinline__ u16 f2bf(float f) {
  union { float f; unsigned u; } v; v.f = f;
  unsigned u = v.u;
  unsigned r = (u + 0x7fffu + ((u >> 16) & 1u)) >> 16;  // RNE
  return (u16)r;
}
__device__ __forceinline__ float bf2f(u16 h) {
  union { unsigned u; float f; } v; v.u = ((unsigned)h) << 16; return v.f;
}

// ---------- transpose + fp32->bf16 convert: W [K][N] f32  ->  Wt [N][K] bf16
__global__ __launch_bounds__(256) void kxpose(const float* __restrict__ W,
                                              u16* __restrict__ Wt,
                                              int K, int N) {
  __shared__ float t[64][65];
  int kb = blockIdx.y * 64, nb = blockIdx.x * 64;
  int tid = threadIdx.x;
#pragma unroll
  for (int it = 0; it < 16; ++it) {
    int idx = it * 256 + tid;
    int r = idx >> 6, c = idx & 63;
    t[r][c] = W[(size_t)(kb + r) * N + nb + c];
  }
  __syncthreads();
#pragma unroll
  for (int it = 0; it < 16; ++it) {
    int idx = it * 256 + tid;
    int rn = idx >> 6, ck = idx & 63;
    Wt[(size_t)(nb + rn) * K + kb + ck] = f2bf(t[ck][rn]);
  }
}

// ---------- RMSNorm: x [rows][2048] f32 -> out bf16
__global__ __launch_bounds__(256) void krmsnorm(const float* __restrict__ x,
                                                const float* __restrict__ w,
                                                u16* __restrict__ out) {
  int row = blockIdx.x, tid = threadIdx.x;
  const float* xr = x + (size_t)row * DIM;
  float4 a = *(const float4*)(xr + tid * 8);
  float4 b = *(const float4*)(xr + tid * 8 + 4);
  float ss = a.x * a.x + a.y * a.y + a.z * a.z + a.w * a.w +
             b.x * b.x + b.y * b.y + b.z * b.z + b.w * b.w;
#pragma unroll
  for (int off = 1; off < 64; off <<= 1) ss += __shfl_xor(ss, off, 64);
  __shared__ float red[4];
  if ((tid & 63) == 0) red[tid >> 6] = ss;
  __syncthreads();
  float tot = red[0] + red[1] + red[2] + red[3];
  float sc = rsqrtf(tot * (1.0f / DIM) + 1e-5f);
  float xs[8] = {a.x, a.y, a.z, a.w, b.x, b.y, b.z, b.w};
  const float* wr = w + tid * 8;
  u16 o[8];
#pragma unroll
  for (int j = 0; j < 8; ++j) o[j] = f2bf(xs[j] * sc * wr[j]);
  *(int4*)(out + (size_t)row * DIM + tid * 8) = *(const int4*)o;
}

// ---------- RoPE on q (in-place, bf16). one thread per (row, head, pair)
__global__ __launch_bounds__(256) void krope_q(u16* __restrict__ q,
                                               const float* __restrict__ fc) {
  int t = blockIdx.x * 256 + threadIdx.x;           // 2048*16*64 = 2^21
  int j = t & 63;
  int h = (t >> 6) & (NH - 1);
  int row = t >> 10;
  int s = row & (SEQ - 1);
  size_t off = (size_t)row * DIM + h * HD + 2 * j;
  unsigned pk = *(unsigned*)(q + off);
  float x0 = bf2f((u16)pk), x1 = bf2f((u16)(pk >> 16));
  float cs = fc[s * HD + 2 * j], sn = fc[s * HD + 2 * j + 1];
  float y0 = x0 * cs - x1 * sn;
  float y1 = x0 * sn + x1 * cs;
  *(unsigned*)(q + off) = (unsigned)f2bf(y0) | ((unsigned)f2bf(y1) << 16);
}

// ---------- RoPE on k (in-place bf16) + write fp32 cache_k
__global__ __launch_bounds__(256) void krope_k(u16* __restrict__ k,
                                               const float* __restrict__ fc,
                                               float* __restrict__ ck) {
  int t = blockIdx.x * 256 + threadIdx.x;           // 2048*4*64 = 2^19
  int j = t & 63;
  int g = (t >> 6) & (NKV - 1);
  int row = t >> 8;
  int s = row & (SEQ - 1);
  size_t off = (size_t)row * (NKV * HD) + g * HD + 2 * j;
  unsigned pk = *(unsigned*)(k + off);
  float x0 = bf2f((u16)pk), x1 = bf2f((u16)(pk >> 16));
  float cs = fc[s * HD + 2 * j], sn = fc[s * HD + 2 * j + 1];
  float y0 = x0 * cs - x1 * sn;
  float y1 = x0 * sn + x1 * cs;
  *(unsigned*)(k + off) = (unsigned)f2bf(y0) | ((unsigned)f2bf(y1) << 16);
  ck[off] = y0;
  ck[off + 1] = y1;
}

// ---------- GEMM: C[2048][N] = A[2048][K](bf16) * Bt[N][K](bf16)^T, fused epilogues
// EPI 0: qkv-route (cols 0..2047 -> o0 bf16 stride 2048; 2048..2559 -> o1 bf16 stride 512;
//        2560..3071 -> of f32 + o2 bf16, stride 512)
// EPI 1: o0 bf16 stride N
// EPI 2: of f32 = acc + res (stride N)
// EPI 3: o0 bf16 = silu(gin)*acc (stride N)
template <int EPI>
__global__ __launch_bounds__(256) void kgemm(
    const u16* __restrict__ A, const u16* __restrict__ Bt, int N, int K,
    u16* o0, u16* __restrict__ o1, u16* __restrict__ o2,
    float* of, const float* res, const u16* gin) {
  __shared__ u16 As[128][40];
  __shared__ u16 Bs[128][40];
  int bn = blockIdx.x * 128, bm = blockIdx.y * 128;
  int tid = threadIdx.x, lane = tid & 63, wid = tid >> 6;
  int wm = (wid >> 1) * 64, wn = (wid & 1) * 64;
  int r16 = lane & 15, grp = lane >> 4;
  f32x4 acc[4][4] = {};
  int ar = tid >> 2, ak = (tid & 3) * 8;
  const u16* Arow0 = A + (size_t)(bm + ar) * K + ak;
  const u16* Arow1 = Arow0 + (size_t)64 * K;
  const u16* Brow0 = Bt + (size_t)(bn + ar) * K + ak;
  const u16* Brow1 = Brow0 + (size_t)64 * K;
  for (int k0 = 0; k0 < K; k0 += 32) {
    *(int4*)&As[ar][ak] = *(const int4*)(Arow0 + k0);
    *(int4*)&As[ar + 64][ak] = *(const int4*)(Arow1 + k0);
    *(int4*)&Bs[ar][ak] = *(const int4*)(Brow0 + k0);
    *(int4*)&Bs[ar + 64][ak] = *(const int4*)(Brow1 + k0);
    __syncthreads();
    bf16x8 af[4], bf[4];
#pragma unroll
    for (int m = 0; m < 4; ++m) af[m] = *(const bf16x8*)&As[wm + m * 16 + r16][grp * 8];
#pragma unroll
    for (int n = 0; n < 4; ++n) bf[n] = *(const bf16x8*)&Bs[wn + n * 16 + r16][grp * 8];
#pragma unroll
    for (int m = 0; m < 4; ++m)
#pragma unroll
      for (int n = 0; n < 4; ++n)
        acc[m][n] = __builtin_amdgcn_mfma_f32_16x16x32_bf16(af[m], bf[n], acc[m][n], 0, 0, 0);
    __syncthreads();
  }
#pragma unroll
  for (int mi = 0; mi < 4; ++mi) {
#pragma unroll
    for (int ni = 0; ni < 4; ++ni) {
#pragma unroll
      for (int r = 0; r < 4; ++r) {
        int gr = bm + wm + mi * 16 + grp * 4 + r;
        int gc = bn + wn + ni * 16 + r16;
        float v = acc[mi][ni][r];
        if constexpr (EPI == 0) {
          if (gc < DIM) {
            o0[(size_t)gr * DIM + gc] = f2bf(v);
          } else if (gc < DIM + 512) {
            o1[(size_t)gr * 512 + (gc - DIM)] = f2bf(v);
          } else {
            int c2 = gc - (DIM + 512);
            of[(size_t)gr * 512 + c2] = v;
            o2[(size_t)gr * 512 + c2] = f2bf(v);
          }
        } else if constexpr (EPI == 1) {
          o0[(size_t)gr * N + gc] = f2bf(v);
        } else if constexpr (EPI == 2) {
          of[(size_t)gr * N + gc] = v + res[(size_t)gr * N + gc];
        } else {
          float gg = bf2f(gin[(size_t)gr * N + gc]);
          float sg = gg / (1.0f + __expf(-gg));
          o0[(size_t)gr * N + gc] = f2bf(sg * v);
        }
      }
    }
  }
}

// ---------- causal GQA flash attention. 1 wave per (b, h, 16 q rows). KV tiles of 32.
__global__ __launch_bounds__(64) void kattn(const u16* __restrict__ qb,
                                            const u16* __restrict__ kb,
                                            const u16* __restrict__ vb,
                                            u16* __restrict__ ctxb) {
  __shared__ u16 Plds[16][40];
  int l = threadIdx.x;
  int qt = blockIdx.x, h = blockIdx.y, b = blockIdx.z;
  int g = h >> 2;  // J = NH/NKV = 4
  int q0 = qt * 16;
  int r16 = l & 15, grp = l >> 4;
  const float scale = 0.08838834764831845f;  // 1/sqrt(128)
  bf16x8 qf[4];
  {
    const u16* qrow = qb + (size_t)(b * SEQ + q0 + r16) * DIM + h * HD + grp * 8;
#pragma unroll
    for (int c = 0; c < 4; ++c) qf[c] = *(const bf16x8*)(qrow + c * 32);
  }
  f32x4 ctx[8] = {};
  float m = -1e30f, lsum = 0.0f;
  int q_idx = q0 + r16;
  int ttmax = (q0 + 15) >> 5;
  for (int tt = 0; tt <= ttmax; ++tt) {
    int t0 = tt * 32;
    f32x4 d0 = {0.f, 0.f, 0.f, 0.f}, d1 = {0.f, 0.f, 0.f, 0.f};
    const u16* krow0 = kb + (size_t)(b * SEQ + t0 + r16) * (NKV * HD) + g * HD + grp * 8;
    const u16* krow1 = krow0 + 16 * (NKV * HD);
#pragma unroll
    for (int c = 0; c < 4; ++c) {
      bf16x8 kf0 = *(const bf16x8*)(krow0 + c * 32);
      d0 = __builtin_amdgcn_mfma_f32_16x16x32_bf16(kf0, qf[c], d0, 0, 0, 0);
      bf16x8 kf1 = *(const bf16x8*)(krow1 + c * 32);
      d1 = __builtin_amdgcn_mfma_f32_16x16x32_bf16(kf1, qf[c], d1, 0, 0, 0);
    }
    // lane holds S[q = q0+r16][t = t0 + grp*4 + r (+16)]
    float p[8];
    float mx = -1e30f;
#pragma unroll
    for (int r = 0; r < 4; ++r) {
      int tA = t0 + grp * 4 + r;
      float sA = d0[r] * scale;
      if (tA > q_idx) sA = -1e30f;
      float sB = d1[r] * scale;
      if (tA + 16 > q_idx) sB = -1e30f;
      p[r] = sA; p[r + 4] = sB;
      mx = fmaxf(mx, fmaxf(sA, sB));
    }
    mx = fmaxf(mx, __shfl_xor(mx, 16, 64));
    mx = fmaxf(mx, __shfl_xor(mx, 32, 64));
    float mnew = fmaxf(m, mx);
    float psum = 0.f;
#pragma unroll
    for (int i = 0; i < 8; ++i) { p[i] = __expf(p[i] - mnew); psum += p[i]; }
    psum += __shfl_xor(psum, 16, 64);
    psum += __shfl_xor(psum, 32, 64);
    float corr = __expf(m - mnew);
    lsum = lsum * corr + psum;
    m = mnew;
    // P -> LDS in A-frag-friendly [q][t_rel] layout
    *(unsigned*)&Plds[r16][grp * 4] = (unsigned)f2bf(p[0]) | ((unsigned)f2bf(p[1]) << 16);
    *(unsigned*)&Plds[r16][grp * 4 + 2] = (unsigned)f2bf(p[2]) | ((unsigned)f2bf(p[3]) << 16);
    *(unsigned*)&Plds[r16][16 + grp * 4] = (unsigned)f2bf(p[4]) | ((unsigned)f2bf(p[5]) << 16);
    *(unsigned*)&Plds[r16][16 + grp * 4 + 2] = (unsigned)f2bf(p[6]) | ((unsigned)f2bf(p[7]) << 16);
    // rescale ctx (ctx reg r belongs to q_rel = grp*4+r; corr lives at lane q_rel)
    float cf[4];
#pragma unroll
    for (int r = 0; r < 4; ++r) cf[r] = __shfl(corr, grp * 4 + r, 64);
#pragma unroll
    for (int dc = 0; dc < 8; ++dc)
#pragma unroll
      for (int r = 0; r < 4; ++r) ctx[dc][r] *= cf[r];
    bf16x8 pa;
    {
      union { bf16x8 v; int4 q; } u;
      u.q = *(const int4*)&Plds[r16][grp * 8];
      pa = u.v;
    }
    const u16* vbase = vb + (size_t)(b * SEQ + t0 + grp * 8) * (NKV * HD) + g * HD;
#pragma unroll
    for (int dc = 0; dc < 8; ++dc) {
      union { bf16x8 v; u16 u[8]; } vf;
#pragma unroll
      for (int i = 0; i < 8; ++i) vf.u[i] = vbase[(size_t)i * (NKV * HD) + dc * 16 + r16];
      ctx[dc] = __builtin_amdgcn_mfma_f32_16x16x32_bf16(pa, vf.v, ctx[dc], 0, 0, 0);
    }
  }
  float linv = 1.0f / lsum;
  float lf[4];
#pragma unroll
  for (int r = 0; r < 4; ++r) lf[r] = __shfl(linv, grp * 4 + r, 64);
  u16* crow = ctxb + (size_t)(b * SEQ + q0) * DIM + h * HD;
#pragma unroll
  for (int dc = 0; dc < 8; ++dc)
#pragma unroll
    for (int r = 0; r < 4; ++r)
      crow[(size_t)(grp * 4 + r) * DIM + dc * 16 + r16] = f2bf(ctx[dc][r] * lf[r]);
}

extern "C" void kernel_launch(void* const* d_in, const int* in_sizes, int n_in,
                              void* d_out, int out_size, void* d_ws, size_t ws_size,
                              hipStream_t stream) {
  const float* x = (const float*)d_in[0];
  const float* fc = (const float*)d_in[1];
  const float* wq = (const float*)d_in[5];
  const float* wk = (const float*)d_in[6];
  const float* wv = (const float*)d_in[7];
  const float* wo = (const float*)d_in[8];
  const float* wg = (const float*)d_in[9];
  const float* wu = (const float*)d_in[10];
  const float* wd = (const float*)d_in[11];
  const float* anw = (const float*)d_in[12];
  const float* fnw = (const float*)d_in[13];

  float* out_x = (float*)d_out;                       // [2048][2048] f32
  float* out_ck = out_x + (size_t)MROWS * DIM;        // [2048][512] f32
  float* out_cv = out_ck + (size_t)MROWS * NKV * HD;  // [2048][512] f32

  char* ws = (char*)d_ws;
  u16* h_b   = (u16*)(ws);                      // 8 MB   [2048][2048] bf16
  u16* q_b   = (u16*)(ws + (8u << 20));         // 8 MB   [2048][2048]
  u16* k_b   = (u16*)(ws + (16u << 20));        // 2 MB   [2048][512]
  u16* v_b   = (u16*)(ws + (18u << 20));        // 2 MB   [2048][512]
  u16* ctx_b = (u16*)(ws + (20u << 20));        // 8 MB   [2048][2048]
  u16* hf_b  = (u16*)(ws + (28u << 20));        // 8 MB   [2048][2048]
  u16* g_b   = (u16*)(ws + (36u << 20));        // 23 MB  [2048][5632]
  u16* Wt    = (u16*)(ws + (60u << 20));        // 24 MB  transposed bf16 weights

  // QKV weights -> Wt rows [0,2048)=wq^T, [2048,2560)=wk^T, [2560,3072)=wv^T
  kxpose<<<dim3(2048 / 64, 2048 / 64), 256, 0, stream>>>(wq, Wt, 2048, 2048);
  kxpose<<<dim3(512 / 64, 2048 / 64), 256, 0, stream>>>(wk, Wt + (size_t)2048 * 2048, 2048, 512);
  kxpose<<<dim3(512 / 64, 2048 / 64), 256, 0, stream>>>(wv, Wt + (size_t)2560 * 2048, 2048, 512);

  krmsnorm<<<MROWS, 256, 0, stream>>>(x, anw, h_b);
  kgemm<0><<<dim3(3072 / 128, 16), 256, 0, stream>>>(h_b, Wt, 3072, 2048,
                                                     q_b, k_b, v_b, out_cv, nullptr, nullptr);
  krope_q<<<8192, 256, 0, stream>>>(q_b, fc);
  krope_k<<<2048, 256, 0, stream>>>(k_b, fc, out_ck);
  kattn<<<dim3(SEQ / 16, NH, BSZ), 64, 0, stream>>>(q_b, k_b, v_b, ctx_b);

  kxpose<<<dim3(32, 32), 256, 0, stream>>>(wo, Wt, 2048, 2048);
  kgemm<2><<<dim3(16, 16), 256, 0, stream>>>(ctx_b, Wt, 2048, 2048,
                                             nullptr, nullptr, nullptr, out_x, x, nullptr);
  krmsnorm<<<MROWS, 256, 0, stream>>>(out_x, fnw, hf_b);

  kxpose<<<dim3(5632 / 64, 2048 / 64), 256, 0, stream>>>(wg, Wt, 2048, 5632);
  kgemm<1><<<dim3(5632 / 128, 16), 256, 0, stream>>>(hf_b, Wt, 5632, 2048,
                                                     g_b, nullptr, nullptr, nullptr, nullptr, nullptr);
  kxpose<<<dim3(5632 / 64, 2048 / 64), 256, 0, stream>>>(wu, Wt, 2048, 5632);
  kgemm<3><<<dim3(5632 / 128, 16), 256, 0, stream>>>(hf_b, Wt, 5632, 2048,
                                                     g_b, nullptr, nullptr, nullptr, nullptr, g_b);
  kxpose<<<dim3(2048 / 64, 5632 / 64), 256, 0, stream>>>(wd, Wt, 5632, 2048);
  kgemm<2><<<dim3(16, 16), 256, 0, stream>>>(g_b, Wt, 2048, 5632,
                                             nullptr, nullptr, nullptr, out_x, out_x, nullptr);
}

// Round 2
// 535.025 us; speedup vs baseline: 1.1254x; 1.1254x over previous
//
#include <hip/hip_runtime.h>

typedef float f32x4 __attribute__((ext_vector_type(4)));
typedef __bf16 bf16x8 __attribute__((ext_vector_type(8)));
typedef unsigned short u16;

#define DIM 2048
#define SEQ 1024
#define BSZ 2
#define NH 16
#define NKV 4
#define HD 128
#define FFNDIM 5632
#define MROWS (BSZ * SEQ)  // 2048

__device__ __forceinline__ u16 f2bf(float f) {
  union { float f; unsigned u; } v; v.f = f;
  unsigned u = v.u;
  unsigned r = (u + 0x7fffu + ((u >> 16) & 1u)) >> 16;  // RNE
  return (u16)r;
}
__device__ __forceinline__ float bf2f(u16 h) {
  union { unsigned u; float f; } v; v.u = ((unsigned)h) << 16; return v.f;
}

__device__ __forceinline__ void gld16(const void* g, void* l) {
  __builtin_amdgcn_global_load_lds(
      (const __attribute__((address_space(1))) unsigned int*)g,
      (__attribute__((address_space(3))) unsigned int*)l, 16, 0, 0);
}

// ---------- transpose + fp32->bf16 convert: W [K][N] f32  ->  Wt [N][K] bf16
__global__ __launch_bounds__(256) void kxpose(const float* __restrict__ W,
                                              u16* __restrict__ Wt,
                                              int K, int N) {
  __shared__ float t[64][65];
  int kb = blockIdx.y * 64, nb = blockIdx.x * 64;
  int tid = threadIdx.x;
#pragma unroll
  for (int it = 0; it < 16; ++it) {
    int idx = it * 256 + tid;
    int r = idx >> 6, c = idx & 63;
    t[r][c] = W[(size_t)(kb + r) * N + nb + c];
  }
  __syncthreads();
#pragma unroll
  for (int it = 0; it < 16; ++it) {
    int idx = it * 256 + tid;
    int rn = idx >> 6, ck = idx & 63;
    Wt[(size_t)(nb + rn) * K + kb + ck] = f2bf(t[ck][rn]);
  }
}

// ---------- RMSNorm: x [rows][2048] f32 -> out bf16
__global__ __launch_bounds__(256) void krmsnorm(const float* __restrict__ x,
                                                const float* __restrict__ w,
                                                u16* __restrict__ out) {
  int row = blockIdx.x, tid = threadIdx.x;
  const float* xr = x + (size_t)row * DIM;
  float4 a = *(const float4*)(xr + tid * 8);
  float4 b = *(const float4*)(xr + tid * 8 + 4);
  float ss = a.x * a.x + a.y * a.y + a.z * a.z + a.w * a.w +
             b.x * b.x + b.y * b.y + b.z * b.z + b.w * b.w;
#pragma unroll
  for (int off = 1; off < 64; off <<= 1) ss += __shfl_xor(ss, off, 64);
  __shared__ float red[4];
  if ((tid & 63) == 0) red[tid >> 6] = ss;
  __syncthreads();
  float tot = red[0] + red[1] + red[2] + red[3];
  float sc = rsqrtf(tot * (1.0f / DIM) + 1e-5f);
  float xs[8] = {a.x, a.y, a.z, a.w, b.x, b.y, b.z, b.w};
  const float* wr = w + tid * 8;
  u16 o[8];
#pragma unroll
  for (int j = 0; j < 8; ++j) o[j] = f2bf(xs[j] * sc * wr[j]);
  *(int4*)(out + (size_t)row * DIM + tid * 8) = *(const int4*)o;
}

// ---------- RoPE on q (in-place, bf16). one thread per (row, head, pair)
__global__ __launch_bounds__(256) void krope_q(u16* __restrict__ q,
                                               const float* __restrict__ fc) {
  int t = blockIdx.x * 256 + threadIdx.x;           // 2048*16*64 = 2^21
  int j = t & 63;
  int h = (t >> 6) & (NH - 1);
  int row = t >> 10;
  int s = row & (SEQ - 1);
  size_t off = (size_t)row * DIM + h * HD + 2 * j;
  unsigned pk = *(unsigned*)(q + off);
  float x0 = bf2f((u16)pk), x1 = bf2f((u16)(pk >> 16));
  float cs = fc[s * HD + 2 * j], sn = fc[s * HD + 2 * j + 1];
  float y0 = x0 * cs - x1 * sn;
  float y1 = x0 * sn + x1 * cs;
  *(unsigned*)(q + off) = (unsigned)f2bf(y0) | ((unsigned)f2bf(y1) << 16);
}

// ---------- RoPE on k (in-place bf16) + write fp32 cache_k
__global__ __launch_bounds__(256) void krope_k(u16* __restrict__ k,
                                               const float* __restrict__ fc,
                                               float* __restrict__ ck) {
  int t = blockIdx.x * 256 + threadIdx.x;           // 2048*4*64 = 2^19
  int j = t & 63;
  int g = (t >> 6) & (NKV - 1);
  int row = t >> 8;
  int s = row & (SEQ - 1);
  size_t off = (size_t)row * (NKV * HD) + g * HD + 2 * j;
  unsigned pk = *(unsigned*)(k + off);
  float x0 = bf2f((u16)pk), x1 = bf2f((u16)(pk >> 16));
  float cs = fc[s * HD + 2 * j], sn = fc[s * HD + 2 * j + 1];
  float y0 = x0 * cs - x1 * sn;
  float y1 = x0 * sn + x1 * cs;
  *(unsigned*)(k + off) = (unsigned)f2bf(y0) | ((unsigned)f2bf(y1) << 16);
  ck[off] = y0;
  ck[off + 1] = y1;
}

// ---------- GEMM: C[2048][N] = A[2048][K](bf16) * Bt[N][K](bf16)^T
// m97 structure: 128x128 tile, BK=64, global_load_lds width-16 staging into
// linear LDS with XOR-swizzled content (inverse-swizzled global source),
// swizzled ds_read_b128 (conflict-free b128 minimum), 2 barriers per K-step.
// EPI 0: qkv-route; EPI 1: bf16 out; EPI 2: f32 = acc + res; EPI 3: silu(gin)*acc
template <int EPI>
__global__ __launch_bounds__(256) void kgemm(
    const u16* __restrict__ A, const u16* __restrict__ Bt, int N, int K,
    u16* o0, u16* __restrict__ o1, u16* __restrict__ o2,
    float* of, const float* res, const u16* gin) {
  __shared__ u16 As[128 * 64];
  __shared__ u16 Bs[128 * 64];
  int bn = blockIdx.x * 128, bm = blockIdx.y * 128;
  int tid = threadIdx.x, lane = tid & 63, wv = tid >> 6;
  int wm = (wv >> 1) * 64, wn = (wv & 1) * 64;
  int r16 = lane & 15, grp = lane >> 4;
  int srow = lane >> 3;                    // 0..7: row within 8-row chunk
  int schunk = ((lane & 7) ^ srow) * 8;    // inverse-swizzled source k-offset
  f32x4 acc[4][4] = {};
  // wave wv stages rows [wv*32, wv*32+32) of both tiles
  const u16* Abase = A + (size_t)(bm + wv * 32) * K + schunk;
  const u16* Bbase = Bt + (size_t)(bn + wv * 32) * K + schunk;
  u16* AsW = As + wv * 32 * 64;
  u16* BsW = Bs + wv * 32 * 64;
  for (int k0 = 0; k0 < K; k0 += 64) {
#pragma unroll
    for (int j = 0; j < 4; ++j) {
      gld16(Abase + (size_t)(j * 8 + srow) * K + k0, AsW + j * 512);
      gld16(Bbase + (size_t)(j * 8 + srow) * K + k0, BsW + j * 512);
    }
    __syncthreads();
#pragma unroll
    for (int kk = 0; kk < 2; ++kk) {
      int swz = (((kk << 2) | grp) ^ (r16 & 7)) * 8;
      bf16x8 af[4], bfr[4];
#pragma unroll
      for (int m = 0; m < 4; ++m)
        af[m] = *(const bf16x8*)&As[(wm + m * 16 + r16) * 64 + swz];
#pragma unroll
      for (int n = 0; n < 4; ++n)
        bfr[n] = *(const bf16x8*)&Bs[(wn + n * 16 + r16) * 64 + swz];
#pragma unroll
      for (int m = 0; m < 4; ++m)
#pragma unroll
        for (int n = 0; n < 4; ++n)
          acc[m][n] = __builtin_amdgcn_mfma_f32_16x16x32_bf16(af[m], bfr[n], acc[m][n], 0, 0, 0);
    }
    __syncthreads();
  }
#pragma unroll
  for (int mi = 0; mi < 4; ++mi) {
#pragma unroll
    for (int ni = 0; ni < 4; ++ni) {
#pragma unroll
      for (int r = 0; r < 4; ++r) {
        int gr = bm + wm + mi * 16 + grp * 4 + r;
        int gc = bn + wn + ni * 16 + r16;
        float v = acc[mi][ni][r];
        if constexpr (EPI == 0) {
          if (gc < DIM) {
            o0[(size_t)gr * DIM + gc] = f2bf(v);
          } else if (gc < DIM + 512) {
            o1[(size_t)gr * 512 + (gc - DIM)] = f2bf(v);
          } else {
            int c2 = gc - (DIM + 512);
            of[(size_t)gr * 512 + c2] = v;
            o2[(size_t)gr * 512 + c2] = f2bf(v);
          }
        } else if constexpr (EPI == 1) {
          o0[(size_t)gr * N + gc] = f2bf(v);
        } else if constexpr (EPI == 2) {
          of[(size_t)gr * N + gc] = v + res[(size_t)gr * N + gc];
        } else {
          float gg = bf2f(gin[(size_t)gr * N + gc]);
          float sg = gg / (1.0f + __expf(-gg));
          o0[(size_t)gr * N + gc] = f2bf(sg * v);
        }
      }
    }
  }
}

// ---------- causal GQA flash attention. 1 wave per (b, h, 16 q rows). KV tiles of 32.
__global__ __launch_bounds__(64) void kattn(const u16* __restrict__ qb,
                                            const u16* __restrict__ kb,
                                            const u16* __restrict__ vb,
                                            u16* __restrict__ ctxb) {
  __shared__ u16 Plds[16][40];
  int l = threadIdx.x;
  int qt = blockIdx.x, h = blockIdx.y, b = blockIdx.z;
  int g = h >> 2;  // J = NH/NKV = 4
  int q0 = qt * 16;
  int r16 = l & 15, grp = l >> 4;
  const float scale = 0.08838834764831845f;  // 1/sqrt(128)
  bf16x8 qf[4];
  {
    const u16* qrow = qb + (size_t)(b * SEQ + q0 + r16) * DIM + h * HD + grp * 8;
#pragma unroll
    for (int c = 0; c < 4; ++c) qf[c] = *(const bf16x8*)(qrow + c * 32);
  }
  f32x4 ctx[8] = {};
  float m = -1e30f, lsum = 0.0f;
  int q_idx = q0 + r16;
  int ttmax = (q0 + 15) >> 5;
  for (int tt = 0; tt <= ttmax; ++tt) {
    int t0 = tt * 32;
    f32x4 d0 = {0.f, 0.f, 0.f, 0.f}, d1 = {0.f, 0.f, 0.f, 0.f};
    const u16* krow0 = kb + (size_t)(b * SEQ + t0 + r16) * (NKV * HD) + g * HD + grp * 8;
    const u16* krow1 = krow0 + 16 * (NKV * HD);
#pragma unroll
    for (int c = 0; c < 4; ++c) {
      bf16x8 kf0 = *(const bf16x8*)(krow0 + c * 32);
      d0 = __builtin_amdgcn_mfma_f32_16x16x32_bf16(kf0, qf[c], d0, 0, 0, 0);
      bf16x8 kf1 = *(const bf16x8*)(krow1 + c * 32);
      d1 = __builtin_amdgcn_mfma_f32_16x16x32_bf16(kf1, qf[c], d1, 0, 0, 0);
    }
    // lane holds S[q = q0+r16][t = t0 + grp*4 + r (+16)]
    float p[8];
    float mx = -1e30f;
#pragma unroll
    for (int r = 0; r < 4; ++r) {
      int tA = t0 + grp * 4 + r;
      float sA = d0[r] * scale;
      if (tA > q_idx) sA = -1e30f;
      float sB = d1[r] * scale;
      if (tA + 16 > q_idx) sB = -1e30f;
      p[r] = sA; p[r + 4] = sB;
      mx = fmaxf(mx, fmaxf(sA, sB));
    }
    mx = fmaxf(mx, __shfl_xor(mx, 16, 64));
    mx = fmaxf(mx, __shfl_xor(mx, 32, 64));
    float mnew = fmaxf(m, mx);
    float psum = 0.f;
#pragma unroll
    for (int i = 0; i < 8; ++i) { p[i] = __expf(p[i] - mnew); psum += p[i]; }
    psum += __shfl_xor(psum, 16, 64);
    psum += __shfl_xor(psum, 32, 64);
    float corr = __expf(m - mnew);
    lsum = lsum * corr + psum;
    m = mnew;
    // P -> LDS in A-frag-friendly [q][t_rel] layout
    *(unsigned*)&Plds[r16][grp * 4] = (unsigned)f2bf(p[0]) | ((unsigned)f2bf(p[1]) << 16);
    *(unsigned*)&Plds[r16][grp * 4 + 2] = (unsigned)f2bf(p[2]) | ((unsigned)f2bf(p[3]) << 16);
    *(unsigned*)&Plds[r16][16 + grp * 4] = (unsigned)f2bf(p[4]) | ((unsigned)f2bf(p[5]) << 16);
    *(unsigned*)&Plds[r16][16 + grp * 4 + 2] = (unsigned)f2bf(p[6]) | ((unsigned)f2bf(p[7]) << 16);
    // rescale ctx (ctx reg r belongs to q_rel = grp*4+r; corr lives at lane q_rel)
    float cf[4];
#pragma unroll
    for (int r = 0; r < 4; ++r) cf[r] = __shfl(corr, grp * 4 + r, 64);
#pragma unroll
    for (int dc = 0; dc < 8; ++dc)
#pragma unroll
      for (int r = 0; r < 4; ++r) ctx[dc][r] *= cf[r];
    bf16x8 pa;
    {
      union { bf16x8 v; int4 q; } u;
      u.q = *(const int4*)&Plds[r16][grp * 8];
      pa = u.v;
    }
    const u16* vbase = vb + (size_t)(b * SEQ + t0 + grp * 8) * (NKV * HD) + g * HD;
#pragma unroll
    for (int dc = 0; dc < 8; ++dc) {
      union { bf16x8 v; u16 u[8]; } vf;
#pragma unroll
      for (int i = 0; i < 8; ++i) vf.u[i] = vbase[(size_t)i * (NKV * HD) + dc * 16 + r16];
      ctx[dc] = __builtin_amdgcn_mfma_f32_16x16x32_bf16(pa, vf.v, ctx[dc], 0, 0, 0);
    }
  }
  float linv = 1.0f / lsum;
  float lf[4];
#pragma unroll
  for (int r = 0; r < 4; ++r) lf[r] = __shfl(linv, grp * 4 + r, 64);
  u16* crow = ctxb + (size_t)(b * SEQ + q0) * DIM + h * HD;
#pragma unroll
  for (int dc = 0; dc < 8; ++dc)
#pragma unroll
    for (int r = 0; r < 4; ++r)
      crow[(size_t)(grp * 4 + r) * DIM + dc * 16 + r16] = f2bf(ctx[dc][r] * lf[r]);
}

extern "C" void kernel_launch(void* const* d_in, const int* in_sizes, int n_in,
                              void* d_out, int out_size, void* d_ws, size_t ws_size,
                              hipStream_t stream) {
  const float* x = (const float*)d_in[0];
  const float* fc = (const float*)d_in[1];
  const float* wq = (const float*)d_in[5];
  const float* wk = (const float*)d_in[6];
  const float* wv = (const float*)d_in[7];
  const float* wo = (const float*)d_in[8];
  const float* wg = (const float*)d_in[9];
  const float* wu = (const float*)d_in[10];
  const float* wd = (const float*)d_in[11];
  const float* anw = (const float*)d_in[12];
  const float* fnw = (const float*)d_in[13];

  float* out_x = (float*)d_out;                       // [2048][2048] f32
  float* out_ck = out_x + (size_t)MROWS * DIM;        // [2048][512] f32
  float* out_cv = out_ck + (size_t)MROWS * NKV * HD;  // [2048][512] f32

  char* ws = (char*)d_ws;
  u16* h_b   = (u16*)(ws);                      // 8 MB   [2048][2048] bf16
  u16* q_b   = (u16*)(ws + (8u << 20));         // 8 MB   [2048][2048]
  u16* k_b   = (u16*)(ws + (16u << 20));        // 2 MB   [2048][512]
  u16* v_b   = (u16*)(ws + (18u << 20));        // 2 MB   [2048][512]
  u16* ctx_b = (u16*)(ws + (20u << 20));        // 8 MB   [2048][2048]
  u16* hf_b  = (u16*)(ws + (28u << 20));        // 8 MB   [2048][2048]
  u16* g_b   = (u16*)(ws + (36u << 20));        // 23 MB  [2048][5632]
  u16* Wt    = (u16*)(ws + (60u << 20));        // 24 MB  transposed bf16 weights

  // QKV weights -> Wt rows [0,2048)=wq^T, [2048,2560)=wk^T, [2560,3072)=wv^T
  kxpose<<<dim3(2048 / 64, 2048 / 64), 256, 0, stream>>>(wq, Wt, 2048, 2048);
  kxpose<<<dim3(512 / 64, 2048 / 64), 256, 0, stream>>>(wk, Wt + (size_t)2048 * 2048, 2048, 512);
  kxpose<<<dim3(512 / 64, 2048 / 64), 256, 0, stream>>>(wv, Wt + (size_t)2560 * 2048, 2048, 512);

  krmsnorm<<<MROWS, 256, 0, stream>>>(x, anw, h_b);
  kgemm<0><<<dim3(3072 / 128, 16), 256, 0, stream>>>(h_b, Wt, 3072, 2048,
                                                     q_b, k_b, v_b, out_cv, nullptr, nullptr);
  krope_q<<<8192, 256, 0, stream>>>(q_b, fc);
  krope_k<<<2048, 256, 0, stream>>>(k_b, fc, out_ck);
  kattn<<<dim3(SEQ / 16, NH, BSZ), 64, 0, stream>>>(q_b, k_b, v_b, ctx_b);

  kxpose<<<dim3(32, 32), 256, 0, stream>>>(wo, Wt, 2048, 2048);
  kgemm<2><<<dim3(16, 16), 256, 0, stream>>>(ctx_b, Wt, 2048, 2048,
                                             nullptr, nullptr, nullptr, out_x, x, nullptr);
  krmsnorm<<<MROWS, 256, 0, stream>>>(out_x, fnw, hf_b);

  kxpose<<<dim3(5632 / 64, 2048 / 64), 256, 0, stream>>>(wg, Wt, 2048, 5632);
  kgemm<1><<<dim3(5632 / 128, 16), 256, 0, stream>>>(hf_b, Wt, 5632, 2048,
                                                     g_b, nullptr, nullptr, nullptr, nullptr, nullptr);
  kxpose<<<dim3(5632 / 64, 2048 / 64), 256, 0, stream>>>(wu, Wt, 2048, 5632);
  kgemm<3><<<dim3(5632 / 128, 16), 256, 0, stream>>>(hf_b, Wt, 5632, 2048,
                                                     g_b, nullptr, nullptr, nullptr, nullptr, g_b);
  kxpose<<<dim3(2048 / 64, 5632 / 64), 256, 0, stream>>>(wd, Wt, 5632, 2048);
  kgemm<2><<<dim3(16, 16), 256, 0, stream>>>(g_b, Wt, 2048, 5632,
                                             nullptr, nullptr, nullptr, out_x, out_x, nullptr);
}

// Round 3
// 527.478 us; speedup vs baseline: 1.1415x; 1.0143x over previous
//
#include <hip/hip_runtime.h>

typedef float f32x4 __attribute__((ext_vector_type(4)));
typedef __bf16 bf16x8 __attribute__((ext_vector_type(8)));
typedef unsigned short u16;

#define DIM 2048
#define SEQ 1024
#define BSZ 2
#define NH 16
#define NKV 4
#define HD 128
#define FFNDIM 5632
#define MROWS (BSZ * SEQ)  // 2048

__device__ __forceinline__ u16 f2bf(float f) {
  union { float f; unsigned u; } v; v.f = f;
  unsigned u = v.u;
  unsigned r = (u + 0x7fffu + ((u >> 16) & 1u)) >> 16;  // RNE
  return (u16)r;
}
__device__ __forceinline__ float bf2f(u16 h) {
  union { unsigned u; float f; } v; v.u = ((unsigned)h) << 16; return v.f;
}

__device__ __forceinline__ void gld16(const void* g, void* l) {
  __builtin_amdgcn_global_load_lds(
      (const __attribute__((address_space(1))) unsigned int*)g,
      (__attribute__((address_space(3))) unsigned int*)l, 16, 0, 0);
}

// ---------- transpose + fp32->bf16 convert: W [K][N] f32  ->  Wt [N][K] bf16
__global__ __launch_bounds__(256) void kxpose(const float* __restrict__ W,
                                              u16* __restrict__ Wt,
                                              int K, int N) {
  __shared__ float t[64][65];
  int kb = blockIdx.y * 64, nb = blockIdx.x * 64;
  int tid = threadIdx.x;
#pragma unroll
  for (int it = 0; it < 16; ++it) {
    int idx = it * 256 + tid;
    int r = idx >> 6, c = idx & 63;
    t[r][c] = W[(size_t)(kb + r) * N + nb + c];
  }
  __syncthreads();
#pragma unroll
  for (int it = 0; it < 16; ++it) {
    int idx = it * 256 + tid;
    int rn = idx >> 6, ck = idx & 63;
    Wt[(size_t)(nb + rn) * K + kb + ck] = f2bf(t[ck][rn]);
  }
}

// ---------- V transpose: v [b*S+s][g*128+d] bf16 -> Vt [((b*4+g)*128+d)*S + s]
__global__ __launch_bounds__(256) void kvxpose(const u16* __restrict__ v,
                                               u16* __restrict__ vt) {
  __shared__ u16 t[64][66];
  int bg = blockIdx.z;
  int b = bg >> 2, g = bg & 3;
  int s0 = blockIdx.x * 64, d0 = blockIdx.y * 64;
  int tid = threadIdx.x;
  int rr = tid >> 4, cc = (tid & 15) * 4;
#pragma unroll
  for (int it = 0; it < 4; ++it) {
    int r = it * 16 + rr;
    *(uint2*)&t[r][cc] =
        *(const uint2*)(v + (size_t)(b * SEQ + s0 + r) * (NKV * HD) + g * HD + d0 + cc);
  }
  __syncthreads();
#pragma unroll
  for (int it = 0; it < 4; ++it) {
    int r = it * 16 + rr;  // d index within tile
    u16 o[4] = {t[cc][r], t[cc + 1][r], t[cc + 2][r], t[cc + 3][r]};
    *(uint2*)(vt + (size_t)((b * NKV + g) * HD + d0 + r) * SEQ + s0 + cc) = *(const uint2*)o;
  }
}

// ---------- RMSNorm: x [rows][2048] f32 -> out bf16
__global__ __launch_bounds__(256) void krmsnorm(const float* __restrict__ x,
                                                const float* __restrict__ w,
                                                u16* __restrict__ out) {
  int row = blockIdx.x, tid = threadIdx.x;
  const float* xr = x + (size_t)row * DIM;
  float4 a = *(const float4*)(xr + tid * 8);
  float4 b = *(const float4*)(xr + tid * 8 + 4);
  float ss = a.x * a.x + a.y * a.y + a.z * a.z + a.w * a.w +
             b.x * b.x + b.y * b.y + b.z * b.z + b.w * b.w;
#pragma unroll
  for (int off = 1; off < 64; off <<= 1) ss += __shfl_xor(ss, off, 64);
  __shared__ float red[4];
  if ((tid & 63) == 0) red[tid >> 6] = ss;
  __syncthreads();
  float tot = red[0] + red[1] + red[2] + red[3];
  float sc = rsqrtf(tot * (1.0f / DIM) + 1e-5f);
  float xs[8] = {a.x, a.y, a.z, a.w, b.x, b.y, b.z, b.w};
  const float* wr = w + tid * 8;
  u16 o[8];
#pragma unroll
  for (int j = 0; j < 8; ++j) o[j] = f2bf(xs[j] * sc * wr[j]);
  *(int4*)(out + (size_t)row * DIM + tid * 8) = *(const int4*)o;
}

// ---------- RoPE on q (in-place, bf16). one thread per (row, head, pair)
__global__ __launch_bounds__(256) void krope_q(u16* __restrict__ q,
                                               const float* __restrict__ fc) {
  int t = blockIdx.x * 256 + threadIdx.x;           // 2048*16*64 = 2^21
  int j = t & 63;
  int h = (t >> 6) & (NH - 1);
  int row = t >> 10;
  int s = row & (SEQ - 1);
  size_t off = (size_t)row * DIM + h * HD + 2 * j;
  unsigned pk = *(unsigned*)(q + off);
  float x0 = bf2f((u16)pk), x1 = bf2f((u16)(pk >> 16));
  float cs = fc[s * HD + 2 * j], sn = fc[s * HD + 2 * j + 1];
  float y0 = x0 * cs - x1 * sn;
  float y1 = x0 * sn + x1 * cs;
  *(unsigned*)(q + off) = (unsigned)f2bf(y0) | ((unsigned)f2bf(y1) << 16);
}

// ---------- RoPE on k (in-place bf16) + write fp32 cache_k
__global__ __launch_bounds__(256) void krope_k(u16* __restrict__ k,
                                               const float* __restrict__ fc,
                                               float* __restrict__ ck) {
  int t = blockIdx.x * 256 + threadIdx.x;           // 2048*4*64 = 2^19
  int j = t & 63;
  int g = (t >> 6) & (NKV - 1);
  int row = t >> 8;
  int s = row & (SEQ - 1);
  size_t off = (size_t)row * (NKV * HD) + g * HD + 2 * j;
  unsigned pk = *(unsigned*)(k + off);
  float x0 = bf2f((u16)pk), x1 = bf2f((u16)(pk >> 16));
  float cs = fc[s * HD + 2 * j], sn = fc[s * HD + 2 * j + 1];
  float y0 = x0 * cs - x1 * sn;
  float y1 = x0 * sn + x1 * cs;
  *(unsigned*)(k + off) = (unsigned)f2bf(y0) | ((unsigned)f2bf(y1) << 16);
  ck[off] = y0;
  ck[off + 1] = y1;
}

// ---------- GEMM: C[2048][N] = A[2048][K](bf16) * Bt[N][K](bf16)^T
// m97 structure: 128x128 tile, BK=64, global_load_lds width-16 staging into
// linear LDS with XOR-swizzled content (inverse-swizzled global source),
// swizzled ds_read_b128 (conflict-free b128 minimum), 2 barriers per K-step.
// EPI 0: qkv-route; EPI 1: bf16 out; EPI 2: f32 = acc + res; EPI 3: silu(gin)*acc
template <int EPI>
__global__ __launch_bounds__(256) void kgemm(
    const u16* __restrict__ A, const u16* __restrict__ Bt, int N, int K,
    u16* o0, u16* __restrict__ o1, u16* __restrict__ o2,
    float* of, const float* res, const u16* gin) {
  __shared__ u16 As[128 * 64];
  __shared__ u16 Bs[128 * 64];
  int bn = blockIdx.x * 128, bm = blockIdx.y * 128;
  int tid = threadIdx.x, lane = tid & 63, wv = tid >> 6;
  int wm = (wv >> 1) * 64, wn = (wv & 1) * 64;
  int r16 = lane & 15, grp = lane >> 4;
  int srow = lane >> 3;                    // 0..7: row within 8-row chunk
  int schunk = ((lane & 7) ^ srow) * 8;    // inverse-swizzled source k-offset
  f32x4 acc[4][4] = {};
  // wave wv stages rows [wv*32, wv*32+32) of both tiles
  const u16* Abase = A + (size_t)(bm + wv * 32) * K + schunk;
  const u16* Bbase = Bt + (size_t)(bn + wv * 32) * K + schunk;
  u16* AsW = As + wv * 32 * 64;
  u16* BsW = Bs + wv * 32 * 64;
  for (int k0 = 0; k0 < K; k0 += 64) {
#pragma unroll
    for (int j = 0; j < 4; ++j) {
      gld16(Abase + (size_t)(j * 8 + srow) * K + k0, AsW + j * 512);
      gld16(Bbase + (size_t)(j * 8 + srow) * K + k0, BsW + j * 512);
    }
    __syncthreads();
#pragma unroll
    for (int kk = 0; kk < 2; ++kk) {
      int swz = (((kk << 2) | grp) ^ (r16 & 7)) * 8;
      bf16x8 af[4], bfr[4];
#pragma unroll
      for (int m = 0; m < 4; ++m)
        af[m] = *(const bf16x8*)&As[(wm + m * 16 + r16) * 64 + swz];
#pragma unroll
      for (int n = 0; n < 4; ++n)
        bfr[n] = *(const bf16x8*)&Bs[(wn + n * 16 + r16) * 64 + swz];
#pragma unroll
      for (int m = 0; m < 4; ++m)
#pragma unroll
        for (int n = 0; n < 4; ++n)
          acc[m][n] = __builtin_amdgcn_mfma_f32_16x16x32_bf16(af[m], bfr[n], acc[m][n], 0, 0, 0);
    }
    __syncthreads();
  }
#pragma unroll
  for (int mi = 0; mi < 4; ++mi) {
#pragma unroll
    for (int ni = 0; ni < 4; ++ni) {
#pragma unroll
      for (int r = 0; r < 4; ++r) {
        int gr = bm + wm + mi * 16 + grp * 4 + r;
        int gc = bn + wn + ni * 16 + r16;
        float v = acc[mi][ni][r];
        if constexpr (EPI == 0) {
          if (gc < DIM) {
            o0[(size_t)gr * DIM + gc] = f2bf(v);
          } else if (gc < DIM + 512) {
            o1[(size_t)gr * 512 + (gc - DIM)] = f2bf(v);
          } else {
            int c2 = gc - (DIM + 512);
            of[(size_t)gr * 512 + c2] = v;
            o2[(size_t)gr * 512 + c2] = f2bf(v);
          }
        } else if constexpr (EPI == 1) {
          o0[(size_t)gr * N + gc] = f2bf(v);
        } else if constexpr (EPI == 2) {
          of[(size_t)gr * N + gc] = v + res[(size_t)gr * N + gc];
        } else {
          float gg = bf2f(gin[(size_t)gr * N + gc]);
          float sg = gg / (1.0f + __expf(-gg));
          o0[(size_t)gr * N + gc] = f2bf(sg * v);
        }
      }
    }
  }
}

// ---------- causal GQA flash attention. 1 wave per (b, h, 16 q rows). KV tiles of 32.
// V consumed from pre-transposed Vt[b][g][d][s]: PV B-fragment = one bf16x8 load.
__global__ __launch_bounds__(64) void kattn(const u16* __restrict__ qb,
                                            const u16* __restrict__ kb,
                                            const u16* __restrict__ vtb,
                                            u16* __restrict__ ctxb) {
  __shared__ u16 Plds[16][40];
  int l = threadIdx.x;
  int qt = blockIdx.x, h = blockIdx.y, b = blockIdx.z;
  int g = h >> 2;  // J = NH/NKV = 4
  int q0 = qt * 16;
  int r16 = l & 15, grp = l >> 4;
  const float scale = 0.08838834764831845f;  // 1/sqrt(128)
  bf16x8 qf[4];
  {
    const u16* qrow = qb + (size_t)(b * SEQ + q0 + r16) * DIM + h * HD + grp * 8;
#pragma unroll
    for (int c = 0; c < 4; ++c) qf[c] = *(const bf16x8*)(qrow + c * 32);
  }
  const u16* vt = vtb + (size_t)(b * NKV + g) * HD * SEQ;
  f32x4 ctx[8] = {};
  float m = -1e30f, lsum = 0.0f;
  int q_idx = q0 + r16;
  int ttmax = (q0 + 15) >> 5;
  for (int tt = 0; tt <= ttmax; ++tt) {
    int t0 = tt * 32;
    f32x4 d0 = {0.f, 0.f, 0.f, 0.f}, d1 = {0.f, 0.f, 0.f, 0.f};
    const u16* krow0 = kb + (size_t)(b * SEQ + t0 + r16) * (NKV * HD) + g * HD + grp * 8;
    const u16* krow1 = krow0 + 16 * (NKV * HD);
#pragma unroll
    for (int c = 0; c < 4; ++c) {
      bf16x8 kf0 = *(const bf16x8*)(krow0 + c * 32);
      d0 = __builtin_amdgcn_mfma_f32_16x16x32_bf16(kf0, qf[c], d0, 0, 0, 0);
      bf16x8 kf1 = *(const bf16x8*)(krow1 + c * 32);
      d1 = __builtin_amdgcn_mfma_f32_16x16x32_bf16(kf1, qf[c], d1, 0, 0, 0);
    }
    // lane holds S[q = q0+r16][t = t0 + grp*4 + r (+16)]
    float p[8];
    float mx = -1e30f;
#pragma unroll
    for (int r = 0; r < 4; ++r) {
      int tA = t0 + grp * 4 + r;
      float sA = d0[r] * scale;
      if (tA > q_idx) sA = -1e30f;
      float sB = d1[r] * scale;
      if (tA + 16 > q_idx) sB = -1e30f;
      p[r] = sA; p[r + 4] = sB;
      mx = fmaxf(mx, fmaxf(sA, sB));
    }
    mx = fmaxf(mx, __shfl_xor(mx, 16, 64));
    mx = fmaxf(mx, __shfl_xor(mx, 32, 64));
    float mnew = fmaxf(m, mx);
    float psum = 0.f;
#pragma unroll
    for (int i = 0; i < 8; ++i) { p[i] = __expf(p[i] - mnew); psum += p[i]; }
    psum += __shfl_xor(psum, 16, 64);
    psum += __shfl_xor(psum, 32, 64);
    float corr = __expf(m - mnew);
    lsum = lsum * corr + psum;
    m = mnew;
    // P -> LDS in A-frag-friendly [q][t_rel] layout
    *(unsigned*)&Plds[r16][grp * 4] = (unsigned)f2bf(p[0]) | ((unsigned)f2bf(p[1]) << 16);
    *(unsigned*)&Plds[r16][grp * 4 + 2] = (unsigned)f2bf(p[2]) | ((unsigned)f2bf(p[3]) << 16);
    *(unsigned*)&Plds[r16][16 + grp * 4] = (unsigned)f2bf(p[4]) | ((unsigned)f2bf(p[5]) << 16);
    *(unsigned*)&Plds[r16][16 + grp * 4 + 2] = (unsigned)f2bf(p[6]) | ((unsigned)f2bf(p[7]) << 16);
    // rescale ctx (ctx reg r belongs to q_rel = grp*4+r; corr lives at lane q_rel)
    float cf[4];
#pragma unroll
    for (int r = 0; r < 4; ++r) cf[r] = __shfl(corr, grp * 4 + r, 64);
#pragma unroll
    for (int dc = 0; dc < 8; ++dc)
#pragma unroll
      for (int r = 0; r < 4; ++r) ctx[dc][r] *= cf[r];
    bf16x8 pa;
    {
      union { bf16x8 v; int4 q; } u;
      u.q = *(const int4*)&Plds[r16][grp * 8];
      pa = u.v;
    }
#pragma unroll
    for (int dc = 0; dc < 8; ++dc) {
      bf16x8 vf = *(const bf16x8*)(vt + (size_t)(dc * 16 + r16) * SEQ + t0 + grp * 8);
      ctx[dc] = __builtin_amdgcn_mfma_f32_16x16x32_bf16(pa, vf, ctx[dc], 0, 0, 0);
    }
  }
  float linv = 1.0f / lsum;
  float lf[4];
#pragma unroll
  for (int r = 0; r < 4; ++r) lf[r] = __shfl(linv, grp * 4 + r, 64);
  u16* crow = ctxb + (size_t)(b * SEQ + q0) * DIM + h * HD;
#pragma unroll
  for (int dc = 0; dc < 8; ++dc)
#pragma unroll
    for (int r = 0; r < 4; ++r)
      crow[(size_t)(grp * 4 + r) * DIM + dc * 16 + r16] = f2bf(ctx[dc][r] * lf[r]);
}

extern "C" void kernel_launch(void* const* d_in, const int* in_sizes, int n_in,
                              void* d_out, int out_size, void* d_ws, size_t ws_size,
                              hipStream_t stream) {
  const float* x = (const float*)d_in[0];
  const float* fc = (const float*)d_in[1];
  const float* wq = (const float*)d_in[5];
  const float* wk = (const float*)d_in[6];
  const float* wv = (const float*)d_in[7];
  const float* wo = (const float*)d_in[8];
  const float* wg = (const float*)d_in[9];
  const float* wu = (const float*)d_in[10];
  const float* wd = (const float*)d_in[11];
  const float* anw = (const float*)d_in[12];
  const float* fnw = (const float*)d_in[13];

  float* out_x = (float*)d_out;                       // [2048][2048] f32
  float* out_ck = out_x + (size_t)MROWS * DIM;        // [2048][512] f32
  float* out_cv = out_ck + (size_t)MROWS * NKV * HD;  // [2048][512] f32

  char* ws = (char*)d_ws;
  u16* h_b   = (u16*)(ws);                      // 8 MB   [2048][2048] bf16
  u16* q_b   = (u16*)(ws + (8u << 20));         // 8 MB   [2048][2048]
  u16* k_b   = (u16*)(ws + (16u << 20));        // 2 MB   [2048][512]
  u16* v_b   = (u16*)(ws + (18u << 20));        // 2 MB   [2048][512]
  u16* ctx_b = (u16*)(ws + (20u << 20));        // 8 MB   [2048][2048]
  u16* hf_b  = (u16*)(ws + (28u << 20));        // 8 MB   [2048][2048]
  u16* g_b   = (u16*)(ws + (36u << 20));        // 23 MB  [2048][5632]
  u16* Wt    = (u16*)(ws + (60u << 20));        // 24 MB  transposed bf16 weights
  u16* vt_b  = h_b;  // reuse: h_b is dead after the QKV GEMM (2 MB needed)

  // QKV weights -> Wt rows [0,2048)=wq^T, [2048,2560)=wk^T, [2560,3072)=wv^T
  kxpose<<<dim3(2048 / 64, 2048 / 64), 256, 0, stream>>>(wq, Wt, 2048, 2048);
  kxpose<<<dim3(512 / 64, 2048 / 64), 256, 0, stream>>>(wk, Wt + (size_t)2048 * 2048, 2048, 512);
  kxpose<<<dim3(512 / 64, 2048 / 64), 256, 0, stream>>>(wv, Wt + (size_t)2560 * 2048, 2048, 512);

  krmsnorm<<<MROWS, 256, 0, stream>>>(x, anw, h_b);
  kgemm<0><<<dim3(3072 / 128, 16), 256, 0, stream>>>(h_b, Wt, 3072, 2048,
                                                     q_b, k_b, v_b, out_cv, nullptr, nullptr);
  krope_q<<<8192, 256, 0, stream>>>(q_b, fc);
  krope_k<<<2048, 256, 0, stream>>>(k_b, fc, out_ck);
  kvxpose<<<dim3(SEQ / 64, HD / 64, BSZ * NKV), 256, 0, stream>>>(v_b, vt_b);
  kattn<<<dim3(SEQ / 16, NH, BSZ), 64, 0, stream>>>(q_b, k_b, vt_b, ctx_b);

  kxpose<<<dim3(32, 32), 256, 0, stream>>>(wo, Wt, 2048, 2048);
  kgemm<2><<<dim3(16, 16), 256, 0, stream>>>(ctx_b, Wt, 2048, 2048,
                                             nullptr, nullptr, nullptr, out_x, x, nullptr);
  krmsnorm<<<MROWS, 256, 0, stream>>>(out_x, fnw, hf_b);

  kxpose<<<dim3(5632 / 64, 2048 / 64), 256, 0, stream>>>(wg, Wt, 2048, 5632);
  kgemm<1><<<dim3(5632 / 128, 16), 256, 0, stream>>>(hf_b, Wt, 5632, 2048,
                                                     g_b, nullptr, nullptr, nullptr, nullptr, nullptr);
  kxpose<<<dim3(5632 / 64, 2048 / 64), 256, 0, stream>>>(wu, Wt, 2048, 5632);
  kgemm<3><<<dim3(5632 / 128, 16), 256, 0, stream>>>(hf_b, Wt, 5632, 2048,
                                                     g_b, nullptr, nullptr, nullptr, nullptr, g_b);
  kxpose<<<dim3(2048 / 64, 5632 / 64), 256, 0, stream>>>(wd, Wt, 5632, 2048);
  kgemm<2><<<dim3(16, 16), 256, 0, stream>>>(g_b, Wt, 2048, 5632,
                                             nullptr, nullptr, nullptr, out_x, out_x, nullptr);
}